// Round 10
// baseline (282.781 us; speedup 1.0000x reference)
//
#include <hip/hip_runtime.h>
#include <hip/hip_bf16.h>
#include <stdint.h>

typedef __attribute__((ext_vector_type(8))) short short8;
typedef __attribute__((ext_vector_type(4))) float f32x4;
typedef __attribute__((ext_vector_type(16))) float f32x16;

#define M_DIM 8192
#define N_DIM 4096
#define K_DIM 4096
#define BM 256
#define BN 256
#define BK 64

static __device__ __forceinline__ unsigned short f32_to_bf16(float f) {
  union { float f; unsigned int u; } v; v.f = f;
  unsigned int u = v.u;
  u += 0x7fffu + ((u >> 16) & 1u);   // round-to-nearest-even
  return (unsigned short)(u >> 16);
}

// ------- fused prep: blocks [0,16384) cast x->bf16; [16384,18432) dequant ----
__global__ void prep_kernel(const float* __restrict__ x,
                            unsigned short* __restrict__ xb,
                            const int* __restrict__ qw,
                            const float* __restrict__ scale,
                            const float* __restrict__ zero,
                            unsigned short* __restrict__ W) {
  if (blockIdx.x < 16384) {
    size_t i = ((size_t)blockIdx.x * blockDim.x + threadIdx.x) * 8;
    float4 v0 = *reinterpret_cast<const float4*>(x + i);
    float4 v1 = *reinterpret_cast<const float4*>(x + i + 4);
    short8 o;
    o[0] = (short)f32_to_bf16(v0.x);
    o[1] = (short)f32_to_bf16(v0.y);
    o[2] = (short)f32_to_bf16(v0.z);
    o[3] = (short)f32_to_bf16(v0.w);
    o[4] = (short)f32_to_bf16(v1.x);
    o[5] = (short)f32_to_bf16(v1.y);
    o[6] = (short)f32_to_bf16(v1.z);
    o[7] = (short)f32_to_bf16(v1.w);
    *reinterpret_cast<short8*>(xb + i) = o;
  } else {
    int idx = (blockIdx.x - 16384) * blockDim.x + threadIdx.x;   // n*128 + c
    int n = idx >> 7;
    int c = idx & 127;
    unsigned int w[8];
#pragma unroll
    for (int k = 0; k < 8; ++k)
      w[k] = (unsigned int)qw[(size_t)k * (N_DIM * 128) + idx];
    int wp = c >> 5, t = c & 31;
#pragma unroll
    for (int s = 0; s < 4; ++s) {
      int r = s ^ 3;
      unsigned int by[8];
#pragma unroll
      for (int k = 0; k < 8; ++k) by[k] = (w[k] >> (8 * r)) & 0xffu;
      int ibase = wp * 1024 + s * 256 + t * 8;
      int g = ibase >> 7;
      float sc = scale[n * 32 + g];
      float zp = zero[n * 32 + g] * 16.0f;
      short8 o;
#pragma unroll
      for (int u = 0; u < 8; ++u) {
        unsigned int q = 0;
#pragma unroll
        for (int k = 0; k < 8; ++k)
          q |= ((by[k] >> (7 - u)) & 1u) << (7 - k);
        o[u] = (short)f32_to_bf16(sc * ((float)q - zp));
      }
      *reinterpret_cast<short8*>(&W[(size_t)n * K_DIM + ibase]) = o;
    }
  }
}

// ---- 256x256 8-region GEMM, mfma_f32_32x32x16_bf16 (R10) ----
// C[M][N] = A[M][K] * B[N][K]^T + bias. 8 waves (2Mx4N), wave out 128x64.
// R10 vs R8 (215us, verified): MFMA shape 16x16x32 -> 32x32x16 (4060 vs 3378
// FLOP/cyc/CU per m119/m06) — floor 621 -> 516 cyc/region; 8 MFMA/region.
// Per wave/region: am_[2 mfrag][4 kstep], bn_[4 kstep]; halves = ksteps
// {0,1}/{2,3} replace the kk-split; WAR legality identical (RD0 overwrites
// regs dead after half 1). Stage/vmcnt/barrier ledger BYTE-IDENTICAL to R8:
// pair staged at region s -> all-waves drain at s+1..s+2 entry -> read >= s+3;
// prologue drains buf0 (vmcnt(2)) + barrier BEFORE cross-slot ds_reads; peel
// pulls the A(1,1,63) drain to p5 (vmcnt(0)).
// Layouts: C/D col=lane&31,row=(reg&3)+8*(reg>>2)+4*(lane>>5) [m74/m101];
// A/B: row|col=lane&31, k=(lane>>5)*8+e (same family as verified 16x16 map).

#define VMCNT2 asm volatile("s_waitcnt vmcnt(2)" ::: "memory")
#define VMCNT0 asm volatile("s_waitcnt vmcnt(0)" ::: "memory")
#define NOOP ((void)0)
#define SB0 __builtin_amdgcn_sched_barrier(0)

#define STG(G, GROWB, KT, LDSC) do {                                           \
  const unsigned short* sb_ = (G) + ((size_t)(GROWB) * K_DIM + (KT) * 64);     \
  __builtin_amdgcn_global_load_lds(                                            \
      (const __attribute__((address_space(1))) void*)(sb_ + s_off0),           \
      (__attribute__((address_space(3))) void*)(smem + (LDSC) + wslot),        \
      16, 0, 0);                                                               \
  __builtin_amdgcn_global_load_lds(                                            \
      (const __attribute__((address_space(1))) void*)(sb_ + s_off1),           \
      (__attribute__((address_space(3))) void*)(smem + (LDSC) + 8192 + wslot), \
      16, 0, 0);                                                               \
} while (0)
#define STG_A(BUF, H, KT) STG(Ag, m0 + (H)*128, (KT), ((BUF)*2 + (H)) * 16384)
#define STG_B(BUF, H, KT) STG(Bg, n0 + (H)*128, (KT), 65536 + ((BUF)*2 + (H)) * 16384)

// A half: ksteps J0,J0+1 for both mfrags (4 x ds_read_b128)
#define LA_H(BUF, QM, J0) do {                                                 \
  _Pragma("unroll") for (int j_ = J0; j_ < (J0) + 2; ++j_)                     \
    _Pragma("unroll") for (int mf_ = 0; mf_ < 2; ++mf_)                        \
      am_[mf_][j_] = *(const short8*)(smem + av[j_] +                          \
          (((BUF)*2 + (QM)) * 16384 + mf_ * 4096));                            \
} while (0)
// B half: ksteps J0,J0+1 (2 x ds_read_b128); 65536 folded into bv[]
#define LB_H(BUF, QN, J0) do {                                                 \
  _Pragma("unroll") for (int j_ = J0; j_ < (J0) + 2; ++j_)                     \
    bn_[j_] = *(const short8*)(smem + bv[j_] + (((BUF)*2 + (QN)) * 16384));    \
} while (0)

// half: ksteps J0,J0+1 x 2 mfrags = 4 MFMA (chains interleaved by mfrag)
#define MFMA_H(QM, QN, J0)                                                     \
  _Pragma("unroll") for (int j_ = J0; j_ < (J0) + 2; ++j_)                     \
    _Pragma("unroll") for (int mf_ = 0; mf_ < 2; ++mf_)                        \
      acc[QM][QN][mf_] = __builtin_amdgcn_mfma_f32_32x32x16_bf16(              \
          am_[mf_][j_], bn_[j_], acc[QM][QN][mf_], 0, 0, 0)

// one region; RD0/RD1 load operands for the NEXT region's MFMAs.
#define REGION(QM, QN, RD0, RD1, STAGE, WAITV) do {                            \
  __builtin_amdgcn_s_barrier();                                                \
  WAITV;                                                                       \
  SB0;                                                                         \
  __builtin_amdgcn_s_setprio(1);                                               \
  STAGE;                                                                       \
  MFMA_H(QM, QN, 0);                                                           \
  RD0;                                                                         \
  SB0;                                                                         \
  MFMA_H(QM, QN, 2);                                                           \
  RD1;                                                                         \
  SB0;                                                                         \
  __builtin_amdgcn_s_setprio(0);                                               \
} while (0)

__global__ __launch_bounds__(512, 2) void gemm_kernel(
    const unsigned short* __restrict__ Ag,   // Xb [M][K] bf16
    const unsigned short* __restrict__ Bg,   // Wb [N][K] bf16
    const float* __restrict__ bias,
    float* __restrict__ C) {
  __shared__ __align__(16) char smem[131072];   // A: [0,64K), B: [64K,128K)

  // XCD-aware bijective swizzle: 512 blocks % 8 == 0
  int bid = blockIdx.x;
  int cpx = gridDim.x >> 3;
  int swz = (bid & 7) * cpx + (bid >> 3);
  int tm = swz >> 4;                 // 32 M-tiles
  int tn = swz & 15;                 // 16 N-tiles
  int m0 = tm * BM, n0 = tn * BN;

  int tid = threadIdx.x;
  int lane = tid & 63;
  int wid = tid >> 6;                // 8 waves
  int wr = wid >> 2, wc = wid & 3;   // 2 x 4

  // hoisted lane addressing: per-kstep voffsets (XOR spans bits 4-6, so each
  // kstep j needs its own precomputed offset; mfrag/region are additive imms)
  const int l31 = lane & 31;
  const int khalf16 = (lane >> 5) << 4;
  const int arow = wr * 64 + l31;            // + mfrag*32 via imm (4096 B)
  const int bcol = wc * 32 + l31;
  const int axor = (arow & 7) << 4;
  const int bxor = (bcol & 7) << 4;
  int av[4], bv[4];
#pragma unroll
  for (int j = 0; j < 4; ++j) {
    av[j] = (arow << 7) + ((j * 32 + khalf16) ^ axor);
    bv[j] = 65536 + (bcol << 7) + ((j * 32 + khalf16) ^ bxor);
  }
  const int wslot = (tid >> 6) << 10;
  const int s_lr0 = tid >> 3, s_lr1 = 64 + (tid >> 3);
  const int s_off0 = s_lr0 * K_DIM + (((tid & 7) ^ (s_lr0 & 7)) << 3);
  const int s_off1 = s_lr1 * K_DIM + (((tid & 7) ^ (s_lr1 & 7)) << 3);

  short8 am_[2][4], bn_[4];
  f32x16 acc[2][2][2];               // [qm][qn][mfrag]
#pragma unroll
  for (int i = 0; i < 2; ++i)
#pragma unroll
    for (int j = 0; j < 2; ++j)
#pragma unroll
      for (int m = 0; m < 2; ++m)
#pragma unroll
        for (int e = 0; e < 16; ++e) acc[i][j][m][e] = 0.f;

  // prologue: buf0 <- kt0 (B00,A00,B01,A01), buf1 A10 <- kt1.
  // vmcnt(2): ALL buf0 loads landed; barrier; then cross-slot ds_reads.
  STG_B(0, 0, 0); STG_A(0, 0, 0); STG_B(0, 1, 0); STG_A(0, 1, 0);
  STG_A(1, 0, 1);
  VMCNT2;
  __builtin_amdgcn_s_barrier();
  LA_H(0, 0, 0); LA_H(0, 0, 2); LB_H(0, 0, 0); LB_H(0, 0, 2);  // region-1 operands

  for (int t = 0; t < 31; ++t) {
    const int kt1 = 2 * t + 1;     // buf0 = kt1-1, buf1 = kt1
    REGION(0, 0, LB_H(0,1,0),              LB_H(0,1,2),              STG_B(1,0,kt1),   VMCNT2);
    REGION(0, 1, LA_H(0,1,0),              LA_H(0,1,2),              STG_B(1,1,kt1),   VMCNT2);
    REGION(1, 1, LB_H(0,0,0),              LB_H(0,0,2),              STG_A(1,1,kt1),   VMCNT2);
    REGION(1, 0, LA_H(1,0,0); LB_H(1,0,0), LA_H(1,0,2); LB_H(1,0,2), STG_B(0,0,kt1+1), VMCNT2);
    REGION(0, 0, LB_H(1,1,0),              LB_H(1,1,2),              STG_A(0,0,kt1+1), VMCNT2);
    REGION(0, 1, LA_H(1,1,0),              LA_H(1,1,2),              STG_B(0,1,kt1+1), VMCNT2);
    REGION(1, 1, LB_H(1,0,0),              LB_H(1,0,2),              STG_A(0,1,kt1+1), VMCNT2);
    REGION(1, 0, LA_H(0,0,0); LB_H(0,0,0), LA_H(0,0,2); LB_H(0,0,2), STG_A(1,0,kt1+2), VMCNT2);
  }
  // peeled final iteration: buf0 = 62, buf1 = 63; no OOB stages.
  REGION(0, 0, LB_H(0,1,0),              LB_H(0,1,2),              STG_B(1,0,63), VMCNT2);
  REGION(0, 1, LA_H(0,1,0),              LA_H(0,1,2),              STG_B(1,1,63), VMCNT2);
  REGION(1, 1, LB_H(0,0,0),              LB_H(0,0,2),              STG_A(1,1,63), VMCNT2);
  REGION(1, 0, LA_H(1,0,0); LB_H(1,0,0), LA_H(1,0,2); LB_H(1,0,2), NOOP,          VMCNT2);
  REGION(0, 0, LB_H(1,1,0),              LB_H(1,1,2),              NOOP,          VMCNT0);
  REGION(0, 1, LA_H(1,1,0),              LA_H(1,1,2),              NOOP,          NOOP);
  REGION(1, 1, LB_H(1,0,0),              LB_H(1,0,2),              NOOP,          NOOP);
  REGION(1, 0, NOOP,                     NOOP,                     NOOP,          NOOP);

  // epilogue: 32x32 C/D layout col=lane&31, row=(reg&3)+8*(reg>>2)+4*(lane>>5)
#pragma unroll
  for (int qn = 0; qn < 2; ++qn) {
    int gcol = n0 + qn * 128 + wc * 32 + l31;
    float bvf = bias[gcol];
#pragma unroll
    for (int qm = 0; qm < 2; ++qm)
#pragma unroll
      for (int m = 0; m < 2; ++m) {
        int growb = m0 + qm * 128 + wr * 64 + m * 32 + ((lane >> 5) << 2);
#pragma unroll
        for (int reg = 0; reg < 16; ++reg) {
          int grow = growb + (reg & 3) + 8 * (reg >> 2);
          C[(size_t)grow * N_DIM + gcol] = acc[qm][qn][m][reg] + bvf;
        }
      }
  }
}

extern "C" void kernel_launch(void* const* d_in, const int* in_sizes, int n_in,
                              void* d_out, int out_size, void* d_ws, size_t ws_size,
                              hipStream_t stream) {
  const float* x       = (const float*)d_in[0];
  const int*   qweight = (const int*)d_in[1];
  const float* scale   = (const float*)d_in[2];
  const float* zero    = (const float*)d_in[3];
  const float* bias    = (const float*)d_in[4];
  float* out = (float*)d_out;

  unsigned short* Xb = (unsigned short*)d_ws;                    // 64 MB
  unsigned short* Wb = Xb + (size_t)M_DIM * K_DIM;               // 32 MB

  prep_kernel<<<16384 + 2048, 256, 0, stream>>>(x, Xb, qweight, scale, zero, Wb);
  gemm_kernel<<<(M_DIM / BM) * (N_DIM / BN), 512, 0, stream>>>(Xb, Wb, bias, out);
}

// Round 11
// 260.692 us; speedup vs baseline: 1.0847x; 1.0847x over previous
//
#include <hip/hip_runtime.h>
#include <hip/hip_bf16.h>
#include <stdint.h>

typedef __attribute__((ext_vector_type(8))) short short8;
typedef __attribute__((ext_vector_type(4))) float f32x4;

#define M_DIM 8192
#define N_DIM 4096
#define K_DIM 4096
#define BM 256
#define BN 256
#define BK 64

static __device__ __forceinline__ unsigned short f32_to_bf16(float f) {
  union { float f; unsigned int u; } v; v.f = f;
  unsigned int u = v.u;
  u += 0x7fffu + ((u >> 16) & 1u);   // round-to-nearest-even
  return (unsigned short)(u >> 16);
}

// ------- fused prep: blocks [0,16384) cast x->bf16; [16384,18432) dequant ----
// (R9 component, validated: saved ~4.4us vs two launches)
__global__ void prep_kernel(const float* __restrict__ x,
                            unsigned short* __restrict__ xb,
                            const int* __restrict__ qw,
                            const float* __restrict__ scale,
                            const float* __restrict__ zero,
                            unsigned short* __restrict__ W) {
  if (blockIdx.x < 16384) {
    size_t i = ((size_t)blockIdx.x * blockDim.x + threadIdx.x) * 8;
    float4 v0 = *reinterpret_cast<const float4*>(x + i);
    float4 v1 = *reinterpret_cast<const float4*>(x + i + 4);
    short8 o;
    o[0] = (short)f32_to_bf16(v0.x);
    o[1] = (short)f32_to_bf16(v0.y);
    o[2] = (short)f32_to_bf16(v0.z);
    o[3] = (short)f32_to_bf16(v0.w);
    o[4] = (short)f32_to_bf16(v1.x);
    o[5] = (short)f32_to_bf16(v1.y);
    o[6] = (short)f32_to_bf16(v1.z);
    o[7] = (short)f32_to_bf16(v1.w);
    *reinterpret_cast<short8*>(xb + i) = o;
  } else {
    int idx = (blockIdx.x - 16384) * blockDim.x + threadIdx.x;   // n*128 + c
    int n = idx >> 7;
    int c = idx & 127;
    unsigned int w[8];
#pragma unroll
    for (int k = 0; k < 8; ++k)
      w[k] = (unsigned int)qw[(size_t)k * (N_DIM * 128) + idx];
    int wp = c >> 5, t = c & 31;
#pragma unroll
    for (int s = 0; s < 4; ++s) {
      int r = s ^ 3;
      unsigned int by[8];
#pragma unroll
      for (int k = 0; k < 8; ++k) by[k] = (w[k] >> (8 * r)) & 0xffu;
      int ibase = wp * 1024 + s * 256 + t * 8;
      int g = ibase >> 7;
      float sc = scale[n * 32 + g];
      float zp = zero[n * 32 + g] * 16.0f;
      short8 o;
#pragma unroll
      for (int u = 0; u < 8; ++u) {
        unsigned int q = 0;
#pragma unroll
        for (int k = 0; k < 8; ++k)
          q |= ((by[k] >> (7 - u)) & 1u) << (7 - k);
        o[u] = (short)f32_to_bf16(sc * ((float)q - zp));
      }
      *reinterpret_cast<short8*>(&W[(size_t)n * K_DIM + ibase]) = o;
    }
  }
}

// ---- 256x256 8-region bf16 GEMM — byte-exact R8 (verified: 215us GEMM,
// MfmaUtil 61%, 0 bank conflicts, absmax 1.0) ----
// C[M][N] = A[M][K] * B[N][K]^T + bias. 8 waves (2Mx4N), wave out 128x64.
// Region p: bar; vmcnt(2); SB0; prio1; stage; kk0-MFMA(8); rd(p+1,kk0); SB0;
//           kk1-MFMA(8); rd(p+1,kk1); SB0; prio0.
// No explicit lgkmcnt(0) at entry — compiler emits precise counted lgkm
// waits before each consuming MFMA octet (R8 finding: equivalent to R6 and
// strictly less conservative). Cross-wave visibility ledger:
// pair staged at region s -> all-waves drain (vmcnt after barrier) at
// s+1..s+2 entry -> read at >= s+3. Prologue drains buf0 (vmcnt(2)) +
// barrier BEFORE any cross-slot ds_read (R5 NaN lesson). Peel pulls the
// A(1,1,63) drain to p5 (vmcnt(0)).
// NOTE (R10 lesson): mfma 32x32x16 swap induces 2.9e7 LDS bank conflicts
// under this staging+read pattern (mechanism unexplained by slot-coverage
// models) — 16x16x32 is the validated shape here.

#define VMCNT2 asm volatile("s_waitcnt vmcnt(2)" ::: "memory")
#define VMCNT0 asm volatile("s_waitcnt vmcnt(0)" ::: "memory")
#define NOOP ((void)0)
#define SB0 __builtin_amdgcn_sched_barrier(0)

#define STG(G, GROWB, KT, LDSC) do {                                           \
  const unsigned short* sb_ = (G) + ((size_t)(GROWB) * K_DIM + (KT) * 64);     \
  __builtin_amdgcn_global_load_lds(                                            \
      (const __attribute__((address_space(1))) void*)(sb_ + s_off0),           \
      (__attribute__((address_space(3))) void*)(smem + (LDSC) + wslot),        \
      16, 0, 0);                                                               \
  __builtin_amdgcn_global_load_lds(                                            \
      (const __attribute__((address_space(1))) void*)(sb_ + s_off1),           \
      (__attribute__((address_space(3))) void*)(smem + (LDSC) + 8192 + wslot), \
      16, 0, 0);                                                               \
} while (0)
#define STG_A(BUF, H, KT) STG(Ag, m0 + (H)*128, (KT), ((BUF)*2 + (H)) * 16384)
#define STG_B(BUF, H, KT) STG(Bg, n0 + (H)*128, (KT), 65536 + ((BUF)*2 + (H)) * 16384)

// reads for ONE k-slot (KK literal): 4 A-frags or 2 B-frags
#define LA(BUF, QM, KK) do {                                                   \
  _Pragma("unroll") for (int mf_ = 0; mf_ < 4; ++mf_)                          \
    a_[mf_][KK] = *(const short8*)(smem + ((KK) ? a_off1 : a_off0) +           \
        (((BUF)*2 + (QM)) * 16384 + mf_ * 2048));                              \
} while (0)
#define LB(BUF, QN, KK) do {                                                   \
  _Pragma("unroll") for (int nf_ = 0; nf_ < 2; ++nf_)                          \
    b_[nf_][KK] = *(const short8*)(smem + ((KK) ? b_off1 : b_off0) +           \
        (((BUF)*2 + (QN)) * 16384 + nf_ * 2048));                              \
} while (0)

#define MFMA_KK(QM, QN, KK)                                                    \
  _Pragma("unroll") for (int mf_ = 0; mf_ < 4; ++mf_)                          \
    _Pragma("unroll") for (int nf_ = 0; nf_ < 2; ++nf_)                        \
      acc[QM][QN][mf_][nf_] = __builtin_amdgcn_mfma_f32_16x16x32_bf16(         \
          a_[mf_][KK], b_[nf_][KK], acc[QM][QN][mf_][nf_], 0, 0, 0)

// one region; RD0/RD1 load operands for the NEXT region's MFMAs.
// WAR deps (RD0 overwrites [*][0] read by octet1) keep intra-region order.
#define REGION(QM, QN, RD0, RD1, STAGE, WAITV) do {                            \
  __builtin_amdgcn_s_barrier();                                                \
  WAITV;                                                                       \
  SB0;                                                                         \
  __builtin_amdgcn_s_setprio(1);                                               \
  STAGE;                                                                       \
  MFMA_KK(QM, QN, 0);                                                          \
  RD0;                                                                         \
  SB0;                                                                         \
  MFMA_KK(QM, QN, 1);                                                          \
  RD1;                                                                         \
  SB0;                                                                         \
  __builtin_amdgcn_s_setprio(0);                                               \
} while (0)

__global__ __launch_bounds__(512, 2) void gemm_kernel(
    const unsigned short* __restrict__ Ag,   // Xb [M][K] bf16
    const unsigned short* __restrict__ Bg,   // Wb [N][K] bf16
    const float* __restrict__ bias,
    float* __restrict__ C) {
  __shared__ __align__(16) char smem[131072];   // A: [0,64K), B: [64K,128K)

  // XCD-aware bijective swizzle: 512 blocks % 8 == 0
  int bid = blockIdx.x;
  int cpx = gridDim.x >> 3;
  int swz = (bid & 7) * cpx + (bid >> 3);
  int tm = swz >> 4;                 // 32 M-tiles
  int tn = swz & 15;                 // 16 N-tiles
  int m0 = tm * BM, n0 = tn * BN;

  int tid = threadIdx.x;
  int lane = tid & 63;
  int wid = tid >> 6;                // 8 waves
  int wr = wid >> 2, wc = wid & 3;   // 2 x 4

  // hoisted lane addressing (R4, validated)
  const int xorv = (lane & 7) << 4;
  const int hi4 = (lane >> 4) << 4;
  const int wrbase = wr * 64 + (lane & 15);
  const int wcbase = wc * 32 + (lane & 15);
  const int a_off0 = (wrbase << 7) + (hi4 ^ xorv);
  const int a_off1 = (wrbase << 7) + ((64 | hi4) ^ xorv);
  const int b_off0 = 65536 + (wcbase << 7) + (hi4 ^ xorv);
  const int b_off1 = 65536 + (wcbase << 7) + ((64 | hi4) ^ xorv);
  const int wslot = (tid >> 6) << 10;
  const int s_lr0 = tid >> 3, s_lr1 = 64 + (tid >> 3);
  const int s_off0 = s_lr0 * K_DIM + (((tid & 7) ^ (s_lr0 & 7)) << 3);
  const int s_off1 = s_lr1 * K_DIM + (((tid & 7) ^ (s_lr1 & 7)) << 3);

  short8 a_[4][2], b_[2][2];
  f32x4 acc[2][2][4][2];
#pragma unroll
  for (int i = 0; i < 2; ++i)
#pragma unroll
    for (int j = 0; j < 2; ++j)
#pragma unroll
      for (int mf = 0; mf < 4; ++mf)
#pragma unroll
        for (int nf = 0; nf < 2; ++nf) acc[i][j][mf][nf] = (f32x4){0.f, 0.f, 0.f, 0.f};

  // prologue: buf0 <- kt0 (B00,A00,B01,A01), buf1 A10 <- kt1.
  // vmcnt(2): ALL buf0 loads landed; barrier; then cross-slot ds_reads.
  STG_B(0, 0, 0); STG_A(0, 0, 0); STG_B(0, 1, 0); STG_A(0, 1, 0);
  STG_A(1, 0, 1);
  VMCNT2;
  __builtin_amdgcn_s_barrier();
  LA(0, 0, 0); LB(0, 0, 0); LA(0, 0, 1); LB(0, 0, 1);  // reads for region 1

  for (int t = 0; t < 31; ++t) {
    const int kt1 = 2 * t + 1;     // buf0 = kt1-1, buf1 = kt1
    REGION(0, 0, LB(0,1,0),            LB(0,1,1),            STG_B(1,0,kt1),   VMCNT2);
    REGION(0, 1, LA(0,1,0),            LA(0,1,1),            STG_B(1,1,kt1),   VMCNT2);
    REGION(1, 1, LB(0,0,0),            LB(0,0,1),            STG_A(1,1,kt1),   VMCNT2);
    REGION(1, 0, LA(1,0,0); LB(1,0,0), LA(1,0,1); LB(1,0,1), STG_B(0,0,kt1+1), VMCNT2);
    REGION(0, 0, LB(1,1,0),            LB(1,1,1),            STG_A(0,0,kt1+1), VMCNT2);
    REGION(0, 1, LA(1,1,0),            LA(1,1,1),            STG_B(0,1,kt1+1), VMCNT2);
    REGION(1, 1, LB(1,0,0),            LB(1,0,1),            STG_A(0,1,kt1+1), VMCNT2);
    REGION(1, 0, LA(0,0,0); LB(0,0,0), LA(0,0,1); LB(0,0,1), STG_A(1,0,kt1+2), VMCNT2);
  }
  // peeled final iteration: buf0 = 62, buf1 = 63; no OOB stages.
  // Drain of A11(63) pulled to p5 (vmcnt(0)) so p6's read is barrier-separated.
  REGION(0, 0, LB(0,1,0),            LB(0,1,1),            STG_B(1,0,63), VMCNT2);
  REGION(0, 1, LA(0,1,0),            LA(0,1,1),            STG_B(1,1,63), VMCNT2);
  REGION(1, 1, LB(0,0,0),            LB(0,0,1),            STG_A(1,1,63), VMCNT2);
  REGION(1, 0, LA(1,0,0); LB(1,0,0), LA(1,0,1); LB(1,0,1), NOOP,          VMCNT2);
  REGION(0, 0, LB(1,1,0),            LB(1,1,1),            NOOP,          VMCNT0);
  REGION(0, 1, LA(1,1,0),            LA(1,1,1),            NOOP,          NOOP);
  REGION(1, 1, LB(1,0,0),            LB(1,0,1),            NOOP,          NOOP);
  REGION(1, 0, NOOP,                 NOOP,                 NOOP,          NOOP);

  // epilogue: C/D layout col=lane&15, row=(lane>>4)*4+j
#pragma unroll
  for (int qn = 0; qn < 2; ++qn)
#pragma unroll
    for (int nf = 0; nf < 2; ++nf) {
      int gcol = n0 + qn * 128 + wc * 32 + nf * 16 + (lane & 15);
      float bv = bias[gcol];
#pragma unroll
      for (int qm = 0; qm < 2; ++qm)
#pragma unroll
        for (int mf = 0; mf < 4; ++mf) {
          int grow = m0 + qm * 128 + wr * 64 + mf * 16 + ((lane >> 4) << 2);
          f32x4 v = acc[qm][qn][mf][nf];
#pragma unroll
          for (int j = 0; j < 4; ++j)
            C[(size_t)(grow + j) * N_DIM + gcol] = v[j] + bv;
        }
    }
}

extern "C" void kernel_launch(void* const* d_in, const int* in_sizes, int n_in,
                              void* d_out, int out_size, void* d_ws, size_t ws_size,
                              hipStream_t stream) {
  const float* x       = (const float*)d_in[0];
  const int*   qweight = (const int*)d_in[1];
  const float* scale   = (const float*)d_in[2];
  const float* zero    = (const float*)d_in[3];
  const float* bias    = (const float*)d_in[4];
  float* out = (float*)d_out;

  unsigned short* Xb = (unsigned short*)d_ws;                    // 64 MB
  unsigned short* Wb = Xb + (size_t)M_DIM * K_DIM;               // 32 MB

  prep_kernel<<<16384 + 2048, 256, 0, stream>>>(x, Xb, qweight, scale, zero, Wb);
  gemm_kernel<<<(M_DIM / BM) * (N_DIM / BN), 512, 0, stream>>>(Xb, Wb, bias, out);
}